// Round 11
// baseline (367.921 us; speedup 1.0000x reference)
//
#include <hip/hip_runtime.h>
#include <hip/hip_bf16.h>

#define N_NODES 4096
#define FEAT    255
#define NB      8
#define NT      16384
#define NG      4

typedef __attribute__((ext_vector_type(8))) short          short8;
typedef __attribute__((ext_vector_type(8))) __bf16         bf16x8;
typedef __attribute__((ext_vector_type(4))) float          f32x4;
typedef __attribute__((ext_vector_type(4))) unsigned short ushort4v;

__device__ __forceinline__ unsigned short f2bf(float f) {
  unsigned int u = __builtin_bit_cast(unsigned int, f);
  u += 0x7fffu + ((u >> 16) & 1u);           // RNE (inputs are finite)
  return (unsigned short)(u >> 16);
}

__device__ __forceinline__ f32x4 mfma16(short8 a, short8 b, f32x4 c) {
  return __builtin_amdgcn_mfma_f32_16x16x32_bf16(
      __builtin_bit_cast(bf16x8, a), __builtin_bit_cast(bf16x8, b), c, 0, 0, 0);
}

// async global->LDS, 16B per lane; lds dest must be wave-uniform base (HW adds lane*16)
__device__ __forceinline__ void gload_lds16(const void* g, void* l) {
  __builtin_amdgcn_global_load_lds((__attribute__((address_space(1))) void*)(void*)g,
                                   (__attribute__((address_space(3))) void*)l, 16, 0, 0);
}

// ---------------------------------------------------------------- deg + bf16 cvt
__global__ __launch_bounds__(256)
void deg_cvt(const float* __restrict__ adj, unsigned short* __restrict__ adjbf,
             float* __restrict__ deg)
{
  const int n = blockIdx.x;
  const int tid = threadIdx.x;
  const float* row = adj + (size_t)n * N_NODES;
  float s = 0.f;
#pragma unroll
  for (int it = 0; it < 4; ++it) {
    int idx = it * 1024 + tid * 4;
    float4 v = *(const float4*)(row + idx);
    s += (v.x + v.y) + (v.z + v.w);
    ushort4v o;
    o[0] = f2bf(v.x); o[1] = f2bf(v.y); o[2] = f2bf(v.z); o[3] = f2bf(v.w);
    *(ushort4v*)(adjbf + (size_t)n * N_NODES + idx) = o;
  }
#pragma unroll
  for (int off = 32; off > 0; off >>= 1) s += __shfl_xor(s, off);
  __shared__ float ws4[4];
  if ((tid & 63) == 0) ws4[tid >> 6] = s;
  __syncthreads();
  if (tid == 0) deg[n] = (ws4[0] + ws4[1]) + (ws4[2] + ws4[3]);
}

// ---------------------------------------------------------------- top-8 (tie: lower idx)
__global__ __launch_bounds__(256)
void topk_kernel(const float* __restrict__ deg, int* __restrict__ brk)
{
  __shared__ float v[N_NODES];
  __shared__ float wv[4];
  __shared__ int   wi[4];
  const int tid = threadIdx.x;
  for (int i = tid; i < N_NODES; i += 256) v[i] = deg[i];
  __syncthreads();
  for (int it = 0; it < NB; ++it) {
    float best = -1e30f; int bidx = 0x7fffffff;
#pragma unroll
    for (int k = 0; k < N_NODES / 256; ++k) {
      int i = k * 256 + tid;
      float x = v[i];
      if (x > best) { best = x; bidx = i; }   // ascending scan: ties keep lower idx
    }
#pragma unroll
    for (int off = 1; off < 64; off <<= 1) {
      float ov = __shfl_xor(best, off);
      int   oi = __shfl_xor(bidx, off);
      if (ov > best || (ov == best && oi < bidx)) { best = ov; bidx = oi; }
    }
    if ((tid & 63) == 0) { wv[tid >> 6] = best; wi[tid >> 6] = bidx; }
    __syncthreads();
    if (tid == 0) {
      float bb = wv[0]; int bbi = wi[0];
#pragma unroll
      for (int k = 1; k < 4; ++k)
        if (wv[k] > bb || (wv[k] == bb && wi[k] < bbi)) { bb = wv[k]; bbi = wi[k]; }
      brk[it] = bbi;
      v[bbi] = -1e30f;
    }
    __syncthreads();
  }
}

// ---------------------------------------------------------------- fused prep: gemm0 | extract_cols | w2t
#define G0R 8
__global__ __launch_bounds__(256)
void prep_kernel(const float* __restrict__ X, const float* __restrict__ W1,
                 const float* __restrict__ adj, const int* __restrict__ brk,
                 const float* __restrict__ W2,
                 unsigned short* __restrict__ Yt, float* __restrict__ adjcol,
                 unsigned short* __restrict__ W2t)
{
  __shared__ float xr[G0R][256];
  const int bid = blockIdx.x;
  const int tid = threadIdx.x;
  if (bid < 512) {
    const int m0 = bid * G0R;
    for (int i = tid; i < G0R * FEAT; i += 256) {
      int r = i / FEAT, c = i - r * FEAT;
      xr[r][c] = X[(size_t)(m0 + r) * FEAT + c];
    }
    __syncthreads();
    const int d = tid;
    float s[G0R] = {};
    for (int fq = 0; fq < 252; fq += 4) {
      float w0 = W1[(fq + 0) * 256 + d];
      float w1 = W1[(fq + 1) * 256 + d];
      float w2 = W1[(fq + 2) * 256 + d];
      float w3 = W1[(fq + 3) * 256 + d];
#pragma unroll
      for (int r = 0; r < G0R; ++r) {
        float4 x4 = *(const float4*)&xr[r][fq];
        s[r] = fmaf(x4.x, w0, s[r]);
        s[r] = fmaf(x4.y, w1, s[r]);
        s[r] = fmaf(x4.z, w2, s[r]);
        s[r] = fmaf(x4.w, w3, s[r]);
      }
    }
    for (int f = 252; f < FEAT; ++f) {
      float wv = W1[f * 256 + d];
#pragma unroll
      for (int r = 0; r < G0R; ++r) s[r] = fmaf(xr[r][f], wv, s[r]);
    }
#pragma unroll
    for (int r = 0; r < G0R; ++r)
      Yt[(size_t)d * N_NODES + m0 + r] = f2bf(s[r]);
  } else if (bid < 528) {
    const int n = (bid - 512) * 256 + tid;
#pragma unroll
    for (int b = 0; b < NB; ++b)
      adjcol[b * N_NODES + n] = adj[(size_t)n * N_NODES + brk[b]];
  } else {
    const int k = bid - 528, d = tid;
    W2t[(size_t)d * 256 + k] = f2bf(W2[(size_t)k * 256 + d]);
  }
}

// ---------------------------------------------------------------- bf16 GEMM, C = A @ Bt^T
// m97 structure + T2 XOR-swizzle (verified r7: BANK_CONFLICT 2.5e7 -> 0).
// OUTBF: emit bf16 C in [b][n][k2] layout (b = col>>8, k2 = col&255) for ln staging.
// !OUTBF: fp32 C, K-split partial per blockIdx.z at C + z*M*Nn.
template<int BM, int BN, int BK, int FM, int FN, bool OUTBF>
__global__ __launch_bounds__(256)
void gemm_bt(const unsigned short* __restrict__ A, const unsigned short* __restrict__ Bt,
             void* __restrict__ Cv, int M, int Nn, int K)
{
  static_assert(BK == 64, "staging/swizzle math assumes BK=64 (128 B = 8 chunks/row)");
  static_assert(BM == 2 * FM * 16 && BN == 2 * FN * 16, "2x2 wave grid");
  __shared__ unsigned short As[BM * BK];
  __shared__ unsigned short Bs[BN * BK];
  const int tid  = threadIdx.x;
  const int lane = tid & 63;
  const int w    = tid >> 6;
  const int wr   = w >> 1, wc = w & 1;
  const int lhi  = lane >> 4, llo = lane & 15;
  const int brow = blockIdx.x * BM;
  const int bcol = blockIdx.y * BN;
  const int Kper = K / gridDim.z;
  const int kbeg = blockIdx.z * Kper;

  f32x4 acc[FM][FN];
  const f32x4 z = {0.f, 0.f, 0.f, 0.f};
#pragma unroll
  for (int m = 0; m < FM; ++m)
#pragma unroll
    for (int n = 0; n < FN; ++n) acc[m][n] = z;

  for (int k0 = kbeg; k0 < kbeg + Kper; k0 += BK) {
    __syncthreads();
#pragma unroll
    for (int i = 0; i < (BM * BK * 2) / 4096; ++i) {
      int byte = i * 4096 + tid * 16;            // linear LDS byte offset
      int row  = byte >> 7;                      // 128 B per row
      int sc   = ((byte >> 4) & 7) ^ (row & 7);  // swizzled source chunk
      gload_lds16(A + (size_t)(brow + row) * K + k0 + sc * 8,
                  As + ((i * 4096 + w * 1024) >> 1));
    }
#pragma unroll
    for (int i = 0; i < (BN * BK * 2) / 4096; ++i) {
      int byte = i * 4096 + tid * 16;
      int row  = byte >> 7;
      int sc   = ((byte >> 4) & 7) ^ (row & 7);
      gload_lds16(Bt + (size_t)(bcol + row) * K + k0 + sc * 8,
                  Bs + ((i * 4096 + w * 1024) >> 1));
    }
    __syncthreads();
#pragma unroll
    for (int kk = 0; kk < BK; kk += 32) {
      short8 fa[FM], fb[FN];
#pragma unroll
      for (int m = 0; m < FM; ++m) {
        const int ar = wr * FM * 16 + m * 16 + llo;
        const int ac = ((kk >> 3) + lhi) ^ (ar & 7);   // same involution on read
        fa[m] = *(const short8*)&As[ar * BK + ac * 8];
      }
#pragma unroll
      for (int n = 0; n < FN; ++n) {
        const int br = wc * FN * 16 + n * 16 + llo;
        const int bc = ((kk >> 3) + lhi) ^ (br & 7);
        fb[n] = *(const short8*)&Bs[br * BK + bc * 8];
      }
#pragma unroll
      for (int m = 0; m < FM; ++m)
#pragma unroll
        for (int n = 0; n < FN; ++n)
          acc[m][n] = mfma16(fa[m], fb[n], acc[m][n]);
    }
  }
#pragma unroll
  for (int m = 0; m < FM; ++m)
#pragma unroll
    for (int n = 0; n < FN; ++n) {
      const int r = brow + wr * FM * 16 + m * 16 + lhi * 4;
      const int c = bcol + wc * FN * 16 + n * 16 + llo;
      if constexpr (OUTBF) {
        unsigned short* Cb = (unsigned short*)Cv;
        const size_t base = ((size_t)(c >> 8) * M) * 256 + (c & 255);
#pragma unroll
        for (int i = 0; i < 4; ++i) Cb[base + (size_t)(r + i) * 256] = f2bf(acc[m][n][i]);
      } else {
        float* cp = (float*)Cv + (size_t)blockIdx.z * M * Nn + (size_t)r * Nn + c;
#pragma unroll
        for (int i = 0; i < 4; ++i) cp[(size_t)i * Nn] = acc[m][n][i];
      }
    }
}

// ---------------------------------------------------------------- Ht[b*256+d][m] = bf16(relu(sum4(basep)+b1+adjcol*W1last))
// LDS-staged (padded [128][33], conflict-free), coalesced 256B Ht writes.
// grid (32, NB, 2): m-tile 128, d-half 128 per block.
__global__ __launch_bounds__(256)
void h_kernel(const float* __restrict__ basep, const float* __restrict__ adjcol,
              const float* __restrict__ b1, const float* __restrict__ W1,
              unsigned short* __restrict__ Ht)
{
  __shared__ float bs[128][33];
  const int tid  = threadIdx.x;
  const int m0   = blockIdx.x * 128;
  const int b    = blockIdx.y;
  const int dh   = blockIdx.z;
  const int ml   = tid & 127, half = tid >> 7;
  const float ac = adjcol[b * N_NODES + m0 + ml];
  const float* w1l = W1 + 255 * 256;
  for (int c = 0; c < 4; ++c) {
    const int d0 = (dh * 4 + c) * 32;
    __syncthreads();                         // protect bs from previous-iter readers
#pragma unroll
    for (int it = 0; it < 4; ++it) {
      int li = it * 256 + tid;               // 0..1023 -> (m 0..127, q 0..7)
      int m = li >> 3, q = li & 7;
      const float* p = basep + (size_t)(m0 + m) * 256 + d0 + q * 4;
      float4 v0 = *(const float4*)(p);
      float4 v1 = *(const float4*)(p + 1048576);
      float4 v2 = *(const float4*)(p + 2097152);
      float4 v3 = *(const float4*)(p + 3145728);
      bs[m][q * 4 + 0] = ((v0.x + v1.x) + v2.x) + v3.x;
      bs[m][q * 4 + 1] = ((v0.y + v1.y) + v2.y) + v3.y;
      bs[m][q * 4 + 2] = ((v0.z + v1.z) + v2.z) + v3.z;
      bs[m][q * 4 + 3] = ((v0.w + v1.w) + v2.w) + v3.w;
    }
    __syncthreads();
#pragma unroll
    for (int k = 0; k < 16; ++k) {
      int dd = half * 16 + k;
      int d  = d0 + dd;
      float v = bs[ml][dd] + b1[d] + ac * w1l[d];
      v = fmaxf(v, 0.f);
      Ht[(size_t)(b * 256 + d) * N_NODES + m0 + ml] = f2bf(v);
    }
  }
}

// ---------------------------------------------------------------- out = Mcat@W2 + b2, fused layernorm -> holo [n][b][d]
// A-tile (64 rows x 256 k bf16, 32 KB) staged via global_load_lds with the
// r7-verified XOR swizzle (512B rows = 32 chunks, chunk ^= row&7).
__global__ __launch_bounds__(256)
void gemm3_ln(const unsigned short* __restrict__ Mcat2, const unsigned short* __restrict__ W2t,
              const float* __restrict__ b2, const float* __restrict__ gamma,
              const float* __restrict__ beta, float* __restrict__ holo)
{
  __shared__ unsigned short As[64 * 256];    // 32 KB
  const int tid  = threadIdx.x;
  const int w    = tid >> 6, lane = tid & 63;
  const int lhi  = lane >> 4, llo = lane & 15;
  const int n0   = blockIdx.x * 64;
  const int b    = blockIdx.y;
  const int row0 = n0 + w * 16;

#pragma unroll
  for (int i = 0; i < 8; ++i) {              // 64*512B / (256 lanes * 16B) = 8
    int byte = i * 4096 + tid * 16;
    int row  = byte >> 9;                    // 512 B per row
    int sc   = ((byte >> 4) & 31) ^ (row & 7);
    gload_lds16(Mcat2 + ((size_t)b * N_NODES + n0 + row) * 256 + sc * 8,
                As + ((i * 4096 + w * 1024) >> 1));
  }
  __syncthreads();                           // drains gload_lds (vmcnt 0 before barrier)

  f32x4 acc[16];
  const f32x4 z = {0.f, 0.f, 0.f, 0.f};
#pragma unroll
  for (int j = 0; j < 16; ++j) acc[j] = z;

  const int ar = w * 16 + llo;               // local A row
#pragma unroll
  for (int k0 = 0; k0 < 256; k0 += 32) {
    const int ac = ((k0 >> 3) + lhi) ^ (ar & 7);
    const short8 fa = *(const short8*)&As[ar * 256 + ac * 8];
#pragma unroll
    for (int j = 0; j < 16; ++j) {
      const short8 fb = *(const short8*)&W2t[(size_t)(j * 16 + llo) * 256 + k0 + lhi * 8];
      acc[j] = mfma16(fa, fb, acc[j]);
    }
  }
  float b2v[16];
#pragma unroll
  for (int j = 0; j < 16; ++j) b2v[j] = b2[j * 16 + llo];

  float mu[4], rs[4];
#pragma unroll
  for (int i = 0; i < 4; ++i) {
    float s = 0.f;
#pragma unroll
    for (int j = 0; j < 16; ++j) s += acc[j][i] + b2v[j];
    s += __shfl_xor(s, 1); s += __shfl_xor(s, 2);
    s += __shfl_xor(s, 4); s += __shfl_xor(s, 8);
    mu[i] = s * (1.f / 256.f);
  }
#pragma unroll
  for (int i = 0; i < 4; ++i) {
    float q = 0.f;
#pragma unroll
    for (int j = 0; j < 16; ++j) { float d = acc[j][i] + b2v[j] - mu[i]; q += d * d; }
    q += __shfl_xor(q, 1); q += __shfl_xor(q, 2);
    q += __shfl_xor(q, 4); q += __shfl_xor(q, 8);
    rs[i] = rsqrtf(q * (1.f / 256.f) + 1e-5f);
  }
  float* hb = holo + ((size_t)(row0 + lhi * 4) * 8 + b) * 256 + llo;
#pragma unroll
  for (int j = 0; j < 16; ++j) {
    const float gv = gamma[j * 16 + llo];
    const float bt = beta[j * 16 + llo];
#pragma unroll
    for (int i = 0; i < 4; ++i) {
      float x = acc[j][i] + b2v[j];
      hb[(size_t)i * 2048 + j * 16] = (x - mu[i]) * rs[i] * gv + bt;
    }
  }
}

// ---------------------------------------------------------------- gather + product + group mean
// holo [n][b][d]; 4 tuples per block (grid NT/4).
__global__ __launch_bounds__(256)
void gather_k(const float* __restrict__ holo, const int* __restrict__ tc,
              const int* __restrict__ gidx, float* __restrict__ out)
{
  const int t0 = blockIdx.x * 4;
  const int d  = threadIdx.x;
  int g[NB];
#pragma unroll
  for (int b = 0; b < NB; ++b) g[b] = gidx[b];
#pragma unroll
  for (int tt = 0; tt < 4; ++tt) {
    const int t = t0 + tt;
    const int i = tc[t];
    const int j = tc[NT + t];
    const float* hi = holo + (size_t)i * 2048 + d;
    const float* hj = holo + (size_t)j * 2048 + d;
    float a0 = 0.f, a1 = 0.f, a2 = 0.f, a3 = 0.f;
    float c0 = 0.f, c1 = 0.f, c2 = 0.f, c3 = 0.f;
#pragma unroll
    for (int b = 0; b < NB; ++b) {
      const float p = hi[b * 256] * hj[b * 256];
      a0 += (g[b] == 0) ? p : 0.f;  c0 += (g[b] == 0) ? 1.f : 0.f;
      a1 += (g[b] == 1) ? p : 0.f;  c1 += (g[b] == 1) ? 1.f : 0.f;
      a2 += (g[b] == 2) ? p : 0.f;  c2 += (g[b] == 2) ? 1.f : 0.f;
      a3 += (g[b] == 3) ? p : 0.f;  c3 += (g[b] == 3) ? 1.f : 0.f;
    }
    float* ob = out + (size_t)t * 1024 + d;
    ob[0]   = a0 / fmaxf(c0, 1.f);
    ob[256] = a1 / fmaxf(c1, 1.f);
    ob[512] = a2 / fmaxf(c2, 1.f);
    ob[768] = a3 / fmaxf(c3, 1.f);
  }
}

// ----------------------------------------------------------------
extern "C" void kernel_launch(void* const* d_in, const int* in_sizes, int n_in,
                              void* d_out, int out_size, void* d_ws, size_t ws_size,
                              hipStream_t stream)
{
  const float* X     = (const float*)d_in[0];
  const float* adj   = (const float*)d_in[1];
  const float* W1    = (const float*)d_in[2];
  const float* b1    = (const float*)d_in[3];
  const float* W2    = (const float*)d_in[4];
  const float* b2    = (const float*)d_in[5];
  const float* gamma = (const float*)d_in[6];
  const float* beta  = (const float*)d_in[7];
  const int*   tc    = (const int*)d_in[8];
  const int*   gidx  = (const int*)d_in[9];

  char* w = (char*)d_ws;
  size_t off = 0;
  unsigned short* adjbf = (unsigned short*)(w + off);            // 32 MB, dead after gemm2
  float*          holo  = (float*)(w + off);  off += 33554432;   // reuses adjbf region
  unsigned short* Ht    = (unsigned short*)(w + off); off += 16777216;
  unsigned short* Mcat2 = (unsigned short*)(w + off); off += 16777216;  // bf16 [b][n][k]
  float*          basep = (float*)(w + off);  off += 16777216;   // 4 K-split partials
  unsigned short* Yt    = (unsigned short*)(w + off); off += 2097152;
  float*          deg   = (float*)(w + off);  off += 16384;
  int*            brk   = (int*)(w + off);    off += 256;
  float*          adjcol= (float*)(w + off);  off += 131072;
  unsigned short* W2t   = (unsigned short*)(w + off); off += 131072;
  float* out = (float*)d_out;

  deg_cvt     <<<N_NODES, 256, 0, stream>>>(adj, adjbf, deg);
  topk_kernel <<<1, 256, 0, stream>>>(deg, brk);
  prep_kernel <<<784, 256, 0, stream>>>(X, W1, adj, brk, W2, Yt, adjcol, W2t);
  gemm_bt<64, 128, 64, 2, 4, false><<<dim3(N_NODES / 64, 256 / 128, 4), 256, 0, stream>>>(
      adjbf, Yt, basep, N_NODES, 256, N_NODES);
  h_kernel    <<<dim3(N_NODES / 128, NB, 2), 256, 0, stream>>>(basep, adjcol, b1, W1, Ht);
  gemm_bt<128, 128, 64, 4, 4, true><<<dim3(N_NODES / 128, 2048 / 128, 1), 256, 0, stream>>>(
      adjbf, Ht, Mcat2, N_NODES, 2048, N_NODES);
  gemm3_ln    <<<dim3(N_NODES / 64, NB), 256, 0, stream>>>(Mcat2, W2t, b2, gamma, beta, holo);
  gather_k    <<<NT / 4, 256, 0, stream>>>(holo, tc, gidx, out);
}